// Round 4
// baseline (2688.936 us; speedup 1.0000x reference)
//
#include <hip/hip_runtime.h>

typedef unsigned int u32;
typedef unsigned char u8;

#define M_DIM 8192   // B*S = 4*2048
#define K_DIM 4096   // I
#define N_DIM 4096   // O
#define GROUPS 64    // I / GROUP_SIZE

typedef int intx4 __attribute__((ext_vector_type(4)));
typedef int intx16 __attribute__((ext_vector_type(16)));

__device__ __forceinline__ void gload_lds16(const void* g, void* l) {
  __builtin_amdgcn_global_load_lds(
      (const __attribute__((address_space(1))) void*)g,
      (__attribute__((address_space(3))) void*)l, 16, 0, 0);
}

__device__ __forceinline__ float block_absmax(float amax, float* red) {
#pragma unroll
  for (int off = 32; off; off >>= 1)
    amax = fmaxf(amax, __shfl_xor(amax, off, 64));
  const int wave = threadIdx.x >> 6;
  if ((threadIdx.x & 63) == 0) red[wave] = amax;
  __syncthreads();
  return fmaxf(fmaxf(red[0], red[1]), fmaxf(red[2], red[3]));
}

__device__ __forceinline__ u32 pack4(const float* v, float inv) {
  u32 r = 0;
#pragma unroll
  for (int i = 0; i < 4; ++i) {
    int q = (int)__builtin_rintf(v[i] * inv);
    q = q > 127 ? 127 : (q < -127 ? -127 : q);
    r |= ((u32)(u8)(char)q) << (8 * i);
  }
  return r;
}

// ---- fused prep: one dispatch, 12288 blocks (unchanged, verified) ----
// blocks [0, N_DIM): W path — dequant row o, scatter via perm into LDS,
// quantize. blocks [N_DIM, ..): X path — x*cs natural order, quantize.
__global__ __launch_bounds__(256) void prep_all(
    const float* __restrict__ x, const float* __restrict__ cs,
    const u32* __restrict__ qw, const int* __restrict__ perm,
    const float* __restrict__ scales, const float* __restrict__ zeros,
    u8* __restrict__ xq, u8* __restrict__ wq,
    float* __restrict__ sx, float* __restrict__ sw) {
  __shared__ float rowbuf[K_DIM];   // 16 KB (W path only)
  __shared__ float red[4];
  const int t = threadIdx.x;
  const int base = t * 16;
  if (blockIdx.x < N_DIM) {
    const int o = blockIdx.x;
    const u32* qrow = qw + (size_t)o * (K_DIM / 8);
    const float s = scales[o * GROUPS + (t >> 2)];
    const float z = zeros[o * GROUPS + (t >> 2)];
    uint2 w = *(const uint2*)(qrow + 2 * t);   // elements [16t, 16t+16)
    int4 p0 = *(const int4*)(perm + base + 0);
    int4 p1 = *(const int4*)(perm + base + 4);
    int4 p2 = *(const int4*)(perm + base + 8);
    int4 p3 = *(const int4*)(perm + base + 12);
    float v[16];
    float amax = 0.f;
#pragma unroll
    for (int n = 0; n < 8; ++n) {
      v[n]     = (float)((w.x >> (4 * n)) & 15u) * s + z;
      v[8 + n] = (float)((w.y >> (4 * n)) & 15u) * s + z;
      amax = fmaxf(amax, fmaxf(fabsf(v[n]), fabsf(v[8 + n])));
    }
    rowbuf[p0.x] = v[0];  rowbuf[p0.y] = v[1];
    rowbuf[p0.z] = v[2];  rowbuf[p0.w] = v[3];
    rowbuf[p1.x] = v[4];  rowbuf[p1.y] = v[5];
    rowbuf[p1.z] = v[6];  rowbuf[p1.w] = v[7];
    rowbuf[p2.x] = v[8];  rowbuf[p2.y] = v[9];
    rowbuf[p2.z] = v[10]; rowbuf[p2.w] = v[11];
    rowbuf[p3.x] = v[12]; rowbuf[p3.y] = v[13];
    rowbuf[p3.z] = v[14]; rowbuf[p3.w] = v[15];
    amax = block_absmax(amax, red);   // sync inside orders rowbuf too
    amax = fmaxf(amax, 1e-20f);
    const float inv = 127.0f / amax;
    uint4 p;
    p.x = pack4(rowbuf + base + 0, inv);
    p.y = pack4(rowbuf + base + 4, inv);
    p.z = pack4(rowbuf + base + 8, inv);
    p.w = pack4(rowbuf + base + 12, inv);
    *(uint4*)(wq + (size_t)o * K_DIM + base) = p;
    if (t == 0) sw[o] = amax * (1.0f / 127.0f);
  } else {
    const size_t m = blockIdx.x - N_DIM;
    const float* xr = x + m * K_DIM;
    float v[16];
    float amax = 0.f;
#pragma unroll
    for (int j = 0; j < 4; ++j) {
      float4 xv = *(const float4*)(xr + base + j * 4);
      float4 cv = *(const float4*)(cs + base + j * 4);
      v[j * 4 + 0] = xv.x * cv.x;
      v[j * 4 + 1] = xv.y * cv.y;
      v[j * 4 + 2] = xv.z * cv.z;
      v[j * 4 + 3] = xv.w * cv.w;
#pragma unroll
      for (int i = 0; i < 4; ++i) amax = fmaxf(amax, fabsf(v[j * 4 + i]));
    }
    amax = block_absmax(amax, red);
    amax = fmaxf(amax, 1e-20f);
    const float inv = 127.0f / amax;
    uint4 p;
    p.x = pack4(v + 0, inv);
    p.y = pack4(v + 4, inv);
    p.z = pack4(v + 8, inv);
    p.w = pack4(v + 12, inv);
    *(uint4*)(xq + m * K_DIM + base) = p;
    if (t == 0) sx[m] = amax * (1.0f / 127.0f);
  }
}

// ---- gemm: 32x32x32 i8, double-buffer 64 KB -> 2 blocks/CU ----
// 256x256 tile, BK=64, 8 waves (2M x 4N), per-wave 128x64 out.
// T3-minimum schedule, ONE barrier per K-tile:
//   { stage(t+1 -> nxt) ; 12 ds_read from cur ; 16 MFMA (setprio) ;
//     vmcnt(0) ; s_barrier }
// vmcnt(0) drains loads issued a full tile of compute earlier (~free);
// cross-BLOCK overlap (2 blocks/CU, m114 implicit co-schedule) fills the
// matrix pipe during this block's read/barrier window — the mechanism the
// 1-block/CU tri-buffer version lacked (34.6% MfmaUtil).
// Swizzle upgraded to g(r) = ((r>>1)&3) ^ ((r>>3)&3): rows 8 apart now map
// to different 16B slots, so every 16-lane batch of the 32-row frag read
// covers all 8 (parity,slot) bank-groups exactly twice (2-way = free).
// Round-3's g=(r>>1)&3 left rows {r, r+8, r+16, r+24} on one slot ->
// 1.26e7 conflicts. Store: physical slot p of row r holds global chunk
// p ^ g(r); read slot = k ^ g(r); k-half pair via addr^32 since
// (2+hi)^g = (hi^g)^2.
#define BM 256
#define BN 256
#define BK 64
#define KTILES (K_DIM / BK)   // 64

__global__ __launch_bounds__(512, 4) void gemm_i8(
    const u8* __restrict__ A, const u8* __restrict__ B,
    const float* __restrict__ sx, const float* __restrict__ sw,
    const float* __restrict__ bias, float* __restrict__ out) {
  __shared__ __align__(16) u8 As[2][BM * BK];   // 2 x 16 KB
  __shared__ __align__(16) u8 Bs[2][BN * BK];   // 2 x 16 KB
  const int tid = threadIdx.x;
  const int lane = tid & 63;
  const int wave = tid >> 6;
  const int wm = wave >> 2;            // 0..1 -> 128 M-rows
  const int wn = wave & 3;             // 0..3 -> 64 N-cols
  const int l5 = lane & 31;
  const int hi = lane >> 5;            // k-half selector
  const int swz = ((l5 >> 1) & 3) ^ ((l5 >> 3) & 3);
  const int blockN = blockIdx.x * BN;
  const int blockM = blockIdx.y * BM;

  const char* Abase = (const char*)(A + (size_t)blockM * K_DIM);
  const char* Bbase = (const char*)(B + (size_t)blockN * K_DIM);

  // staging: 1024 16B chunks per matrix per tile, 2 per thread per matrix
  // chunk c: row r=c>>2, phys slot p=c&3 holds global chunk p ^ g(r),
  // g(r) = ((r>>1)&3)^((r>>3)&3) = ((c>>3)&3)^((c>>5)&3)
  const int c0 = tid, c1 = tid + 512;
  const int kc0 = (c0 & 3) ^ ((c0 >> 3) & 3) ^ ((c0 >> 5) & 3);
  const int kc1 = (c1 & 3) ^ ((c1 >> 3) & 3) ^ ((c1 >> 5) & 3);
  const size_t gOff0 = (size_t)(c0 >> 2) * K_DIM + kc0 * 16;
  const size_t gOff1 = (size_t)(c1 >> 2) * K_DIM + kc1 * 16;
  const int dOff0 = c0 * 16, dOff1 = c1 * 16;

  // frag base addrs: k-chunk hi at slot hi^g; k-chunk 2+hi = addr^32
  const int aoff = (wm * 128 + l5) * 64 + ((hi ^ swz) << 4);
  const int boff = (wn * 64 + l5) * 64 + ((hi ^ swz) << 4);

  intx16 acc[4][2];
#pragma unroll
  for (int i = 0; i < 4; ++i)
#pragma unroll
    for (int j = 0; j < 2; ++j) acc[i][j] = (intx16)0;

  auto stage = [&](int t, int b) {
    const size_t koff = (size_t)t * BK;
    gload_lds16(Abase + gOff0 + koff, &As[b][dOff0]);
    gload_lds16(Abase + gOff1 + koff, &As[b][dOff1]);
    gload_lds16(Bbase + gOff0 + koff, &Bs[b][dOff0]);
    gload_lds16(Bbase + gOff1 + koff, &Bs[b][dOff1]);
  };

  // prologue
  stage(0, 0);
  asm volatile("s_waitcnt vmcnt(0)" ::: "memory");
  asm volatile("s_barrier" ::: "memory");

  for (int t = 0; t < KTILES; ++t) {
    const int cur = t & 1;
    if (t + 1 < KTILES) stage(t + 1, cur ^ 1);

    const u8* Ab = &As[cur][0];
    const u8* Bb = &Bs[cur][0];
    intx4 b00 = *(const intx4*)(Bb + boff);
    intx4 b01 = *(const intx4*)(Bb + (boff ^ 32));
    intx4 b10 = *(const intx4*)(Bb + boff + 2048);
    intx4 b11 = *(const intx4*)(Bb + (boff ^ 32) + 2048);
    intx4 a00 = *(const intx4*)(Ab + aoff);
    intx4 a01 = *(const intx4*)(Ab + (aoff ^ 32));
    intx4 a10 = *(const intx4*)(Ab + aoff + 2048);
    intx4 a11 = *(const intx4*)(Ab + (aoff ^ 32) + 2048);
    intx4 a20 = *(const intx4*)(Ab + aoff + 4096);
    intx4 a21 = *(const intx4*)(Ab + (aoff ^ 32) + 4096);
    intx4 a30 = *(const intx4*)(Ab + aoff + 6144);
    intx4 a31 = *(const intx4*)(Ab + (aoff ^ 32) + 6144);

    __builtin_amdgcn_s_setprio(1);
    acc[0][0] = __builtin_amdgcn_mfma_i32_32x32x32_i8(a00, b00, acc[0][0], 0, 0, 0);
    acc[0][1] = __builtin_amdgcn_mfma_i32_32x32x32_i8(a00, b10, acc[0][1], 0, 0, 0);
    acc[1][0] = __builtin_amdgcn_mfma_i32_32x32x32_i8(a10, b00, acc[1][0], 0, 0, 0);
    acc[1][1] = __builtin_amdgcn_mfma_i32_32x32x32_i8(a10, b10, acc[1][1], 0, 0, 0);
    acc[2][0] = __builtin_amdgcn_mfma_i32_32x32x32_i8(a20, b00, acc[2][0], 0, 0, 0);
    acc[2][1] = __builtin_amdgcn_mfma_i32_32x32x32_i8(a20, b10, acc[2][1], 0, 0, 0);
    acc[3][0] = __builtin_amdgcn_mfma_i32_32x32x32_i8(a30, b00, acc[3][0], 0, 0, 0);
    acc[3][1] = __builtin_amdgcn_mfma_i32_32x32x32_i8(a30, b10, acc[3][1], 0, 0, 0);
    acc[0][0] = __builtin_amdgcn_mfma_i32_32x32x32_i8(a01, b01, acc[0][0], 0, 0, 0);
    acc[0][1] = __builtin_amdgcn_mfma_i32_32x32x32_i8(a01, b11, acc[0][1], 0, 0, 0);
    acc[1][0] = __builtin_amdgcn_mfma_i32_32x32x32_i8(a11, b01, acc[1][0], 0, 0, 0);
    acc[1][1] = __builtin_amdgcn_mfma_i32_32x32x32_i8(a11, b11, acc[1][1], 0, 0, 0);
    acc[2][0] = __builtin_amdgcn_mfma_i32_32x32x32_i8(a21, b01, acc[2][0], 0, 0, 0);
    acc[2][1] = __builtin_amdgcn_mfma_i32_32x32x32_i8(a21, b11, acc[2][1], 0, 0, 0);
    acc[3][0] = __builtin_amdgcn_mfma_i32_32x32x32_i8(a31, b01, acc[3][0], 0, 0, 0);
    acc[3][1] = __builtin_amdgcn_mfma_i32_32x32x32_i8(a31, b11, acc[3][1], 0, 0, 0);
    __builtin_amdgcn_s_setprio(0);

    if (t + 1 < KTILES) {
      asm volatile("s_waitcnt vmcnt(0)" ::: "memory");   // t+1 landed
      asm volatile("s_barrier" ::: "memory");            // all done reading cur
    }
  }

  // epilogue: col = lane&31, row = (reg&3) + 8*(reg>>2) + 4*hi (verified)
#pragma unroll
  for (int ni = 0; ni < 2; ++ni) {
    const int col = blockN + wn * 64 + ni * 32 + l5;
    const float swv = sw[col];
    const float bv = bias[col];
#pragma unroll
    for (int mi = 0; mi < 4; ++mi) {
      const int row0 = blockM + wm * 128 + mi * 32 + 4 * hi;
#pragma unroll
      for (int rg = 0; rg < 4; ++rg) {
#pragma unroll
        for (int rr = 0; rr < 4; ++rr) {
          const int row = row0 + rg * 8 + rr;
          const float s = sx[row] * swv;
          out[(size_t)row * N_DIM + col] = (float)acc[mi][ni][rg * 4 + rr] * s + bv;
        }
      }
    }
  }
}

extern "C" void kernel_launch(void* const* d_in, const int* in_sizes, int n_in,
                              void* d_out, int out_size, void* d_ws, size_t ws_size,
                              hipStream_t stream) {
  const float* x      = (const float*)d_in[0];
  const float* cs     = (const float*)d_in[1];
  const u32*   qw     = (const u32*)d_in[2];
  const int*   perm   = (const int*)d_in[3];
  const float* scales = (const float*)d_in[4];
  const float* zeros  = (const float*)d_in[5];
  const float* bias   = (const float*)d_in[6];
  float* out = (float*)d_out;

  u8* xq = (u8*)d_ws;                               // 32 MiB: M*K i8 (natural)
  u8* wq = xq + (size_t)M_DIM * K_DIM;              // 16 MiB: N*K i8 (perm-scattered)
  float* sx = (float*)(wq + (size_t)N_DIM * K_DIM); // 32 KiB
  float* sw = sx + M_DIM;                           // 16 KiB

  hipLaunchKernelGGL(prep_all, dim3(N_DIM + M_DIM), dim3(256), 0, stream,
                     x, cs, qw, perm, scales, zeros, xq, wq, sx, sw);
  hipLaunchKernelGGL(gemm_i8, dim3(N_DIM / BN, M_DIM / BM), dim3(512), 0,
                     stream, xq, wq, sx, sw, bias, out);
}

// Round 5
// 400.676 us; speedup vs baseline: 6.7110x; 6.7110x over previous
//
#include <hip/hip_runtime.h>

typedef unsigned int u32;
typedef unsigned char u8;

#define M_DIM 8192   // B*S = 4*2048
#define K_DIM 4096   // I
#define N_DIM 4096   // O
#define GROUPS 64    // I / GROUP_SIZE

typedef int intx4 __attribute__((ext_vector_type(4)));

__device__ __forceinline__ void gload_lds16(const void* g, void* l) {
  __builtin_amdgcn_global_load_lds(
      (const __attribute__((address_space(1))) void*)g,
      (__attribute__((address_space(3))) void*)l, 16, 0, 0);
}

__device__ __forceinline__ float block_absmax(float amax, float* red) {
#pragma unroll
  for (int off = 32; off; off >>= 1)
    amax = fmaxf(amax, __shfl_xor(amax, off, 64));
  const int wave = threadIdx.x >> 6;
  if ((threadIdx.x & 63) == 0) red[wave] = amax;
  __syncthreads();
  return fmaxf(fmaxf(red[0], red[1]), fmaxf(red[2], red[3]));
}

__device__ __forceinline__ u32 pack4(const float* v, float inv) {
  u32 r = 0;
#pragma unroll
  for (int i = 0; i < 4; ++i) {
    int q = (int)__builtin_rintf(v[i] * inv);
    q = q > 127 ? 127 : (q < -127 ? -127 : q);
    r |= ((u32)(u8)(char)q) << (8 * i);
  }
  return r;
}

// ---- fused prep: one dispatch, 12288 blocks (unchanged, verified) ----
// blocks [0, N_DIM): W path — dequant row o, scatter via perm into LDS,
// quantize. blocks [N_DIM, ..): X path — x*cs natural order, quantize.
__global__ __launch_bounds__(256) void prep_all(
    const float* __restrict__ x, const float* __restrict__ cs,
    const u32* __restrict__ qw, const int* __restrict__ perm,
    const float* __restrict__ scales, const float* __restrict__ zeros,
    u8* __restrict__ xq, u8* __restrict__ wq,
    float* __restrict__ sx, float* __restrict__ sw) {
  __shared__ float rowbuf[K_DIM];   // 16 KB (W path only)
  __shared__ float red[4];
  const int t = threadIdx.x;
  const int base = t * 16;
  if (blockIdx.x < N_DIM) {
    const int o = blockIdx.x;
    const u32* qrow = qw + (size_t)o * (K_DIM / 8);
    const float s = scales[o * GROUPS + (t >> 2)];
    const float z = zeros[o * GROUPS + (t >> 2)];
    uint2 w = *(const uint2*)(qrow + 2 * t);   // elements [16t, 16t+16)
    int4 p0 = *(const int4*)(perm + base + 0);
    int4 p1 = *(const int4*)(perm + base + 4);
    int4 p2 = *(const int4*)(perm + base + 8);
    int4 p3 = *(const int4*)(perm + base + 12);
    float v[16];
    float amax = 0.f;
#pragma unroll
    for (int n = 0; n < 8; ++n) {
      v[n]     = (float)((w.x >> (4 * n)) & 15u) * s + z;
      v[8 + n] = (float)((w.y >> (4 * n)) & 15u) * s + z;
      amax = fmaxf(amax, fmaxf(fabsf(v[n]), fabsf(v[8 + n])));
    }
    rowbuf[p0.x] = v[0];  rowbuf[p0.y] = v[1];
    rowbuf[p0.z] = v[2];  rowbuf[p0.w] = v[3];
    rowbuf[p1.x] = v[4];  rowbuf[p1.y] = v[5];
    rowbuf[p1.z] = v[6];  rowbuf[p1.w] = v[7];
    rowbuf[p2.x] = v[8];  rowbuf[p2.y] = v[9];
    rowbuf[p2.z] = v[10]; rowbuf[p2.w] = v[11];
    rowbuf[p3.x] = v[12]; rowbuf[p3.y] = v[13];
    rowbuf[p3.z] = v[14]; rowbuf[p3.w] = v[15];
    amax = block_absmax(amax, red);   // sync inside orders rowbuf too
    amax = fmaxf(amax, 1e-20f);
    const float inv = 127.0f / amax;
    uint4 p;
    p.x = pack4(rowbuf + base + 0, inv);
    p.y = pack4(rowbuf + base + 4, inv);
    p.z = pack4(rowbuf + base + 8, inv);
    p.w = pack4(rowbuf + base + 12, inv);
    *(uint4*)(wq + (size_t)o * K_DIM + base) = p;
    if (t == 0) sw[o] = amax * (1.0f / 127.0f);
  } else {
    const size_t m = blockIdx.x - N_DIM;
    const float* xr = x + m * K_DIM;
    float v[16];
    float amax = 0.f;
#pragma unroll
    for (int j = 0; j < 4; ++j) {
      float4 xv = *(const float4*)(xr + base + j * 4);
      float4 cv = *(const float4*)(cs + base + j * 4);
      v[j * 4 + 0] = xv.x * cv.x;
      v[j * 4 + 1] = xv.y * cv.y;
      v[j * 4 + 2] = xv.z * cv.z;
      v[j * 4 + 3] = xv.w * cv.w;
#pragma unroll
      for (int i = 0; i < 4; ++i) amax = fmaxf(amax, fabsf(v[j * 4 + i]));
    }
    amax = block_absmax(amax, red);
    amax = fmaxf(amax, 1e-20f);
    const float inv = 127.0f / amax;
    uint4 p;
    p.x = pack4(v + 0, inv);
    p.y = pack4(v + 4, inv);
    p.z = pack4(v + 8, inv);
    p.w = pack4(v + 12, inv);
    *(uint4*)(xq + m * K_DIM + base) = p;
    if (t == 0) sx[m] = amax * (1.0f / 127.0f);
  }
}

// ---- gemm: 128x128 tile, 4 waves, 16x16x64 i8, multi-block overlap ----
// Design (round-4 post-mortem): per-wave register footprint cut to ~130
// (acc 4x4x4 = 64) so 2-3 INDEPENDENT blocks co-reside per CU. Blocks
// don't share barriers -> block A's MFMA window covers block B's LDS-read
// window (m114 implicit co-schedule) — the overlap the barrier-locked
// 8-wave/256^2 variants never achieved (34.6% MfmaUtil ceiling).
// All LDS building blocks are the round-0 VERIFIED-zero-conflict ones:
// 16x16x64 frag reads with qs = q ^ ((lr>>1)&3), staging slot p of row r
// holds global chunk p ^ ((r>>1)&3) (pre-swizzled source, linear dest —
// rule-21 both-sides involution). The 32x32 frag pattern carried a fixed
// ~4 cyc/read conflict tax (1.258e7, swizzle-invariant) — abandoned.
// Schedule: dbuf, ONE barrier per K-tile:
//   { stage(t+1 -> nxt); 8 ds_read_b128; 16 MFMA (setprio); vmcnt(0);
//     s_barrier }
// vmcnt(0) drains loads issued a full tile of compute earlier.
// __launch_bounds__(256,2): cap 256 VGPR — round-4 spill disaster came
// from (512,4) forcing a 64-VGPR cap; never again.
#define BM 128
#define BN 128
#define BK 64
#define KTILES (K_DIM / BK)   // 64

__global__ __launch_bounds__(256, 2) void gemm_i8(
    const u8* __restrict__ A, const u8* __restrict__ B,
    const float* __restrict__ sx, const float* __restrict__ sw,
    const float* __restrict__ bias, float* __restrict__ out) {
  __shared__ __align__(16) u8 As[2][BM * BK];   // 2 x 8 KB
  __shared__ __align__(16) u8 Bs[2][BN * BK];   // 2 x 8 KB
  const int tid = threadIdx.x;
  const int lane = tid & 63;
  const int wave = tid >> 6;           // 0..3
  const int wm = wave >> 1;            // 0..1 -> 64 M-rows
  const int wn = wave & 1;             // 0..1 -> 64 N-cols
  const int q = lane >> 4, lr = lane & 15;
  const int qs = q ^ ((lr >> 1) & 3);  // verified conflict-free read slot

  // XCD-aware bijective swizzle (2048 % 8 == 0): contiguous chunk per XCD
  const int wg = blockIdx.x;                    // 0..2047
  const int swzwg = (wg & 7) * 256 + (wg >> 3);
  const int blockN = (swzwg & 31) * BN;         // 32 N-panels
  const int blockM = (swzwg >> 5) * BM;         // 64 M-panels

  const char* Abase = (const char*)(A + (size_t)blockM * K_DIM);
  const char* Bbase = (const char*)(B + (size_t)blockN * K_DIM);

  // staging: 512 chunks per matrix per tile, 2 per thread per matrix
  // chunk c: row r=c>>2, slot p=c&3 holds global chunk p ^ ((r>>1)&3)
  const int c0 = tid, c1 = tid + 256;
  const int kc0 = (c0 & 3) ^ ((c0 >> 3) & 3);
  const int kc1 = (c1 & 3) ^ ((c1 >> 3) & 3);
  const size_t gOff0 = (size_t)(c0 >> 2) * K_DIM + kc0 * 16;
  const size_t gOff1 = (size_t)(c1 >> 2) * K_DIM + kc1 * 16;
  const int dOff0 = c0 * 16, dOff1 = c1 * 16;

  const int aoff = (wm * 64 + lr) * 64 + qs * 16;   // + mi*1024
  const int boff = (wn * 64 + lr) * 64 + qs * 16;   // + ni*1024

  intx4 acc[4][4];
#pragma unroll
  for (int i = 0; i < 4; ++i)
#pragma unroll
    for (int j = 0; j < 4; ++j) acc[i][j] = (intx4)0;

  auto stage = [&](int t, int b) {
    const size_t koff = (size_t)t * BK;
    gload_lds16(Abase + gOff0 + koff, &As[b][dOff0]);
    gload_lds16(Abase + gOff1 + koff, &As[b][dOff1]);
    gload_lds16(Bbase + gOff0 + koff, &Bs[b][dOff0]);
    gload_lds16(Bbase + gOff1 + koff, &Bs[b][dOff1]);
  };

  stage(0, 0);
  asm volatile("s_waitcnt vmcnt(0)" ::: "memory");
  asm volatile("s_barrier" ::: "memory");

  for (int t = 0; t < KTILES; ++t) {
    const int cur = t & 1;
    if (t + 1 < KTILES) stage(t + 1, cur ^ 1);

    const u8* Ab = &As[cur][0];
    const u8* Bb = &Bs[cur][0];
    intx4 af[4], bf[4];
#pragma unroll
    for (int mi = 0; mi < 4; ++mi)
      af[mi] = *(const intx4*)(Ab + aoff + mi * 1024);
#pragma unroll
    for (int ni = 0; ni < 4; ++ni)
      bf[ni] = *(const intx4*)(Bb + boff + ni * 1024);

    __builtin_amdgcn_s_setprio(1);
#pragma unroll
    for (int mi = 0; mi < 4; ++mi)
#pragma unroll
      for (int ni = 0; ni < 4; ++ni)
        acc[mi][ni] = __builtin_amdgcn_mfma_i32_16x16x64_i8(
            af[mi], bf[ni], acc[mi][ni], 0, 0, 0);
    __builtin_amdgcn_s_setprio(0);

    if (t + 1 < KTILES) {
      asm volatile("s_waitcnt vmcnt(0)" ::: "memory");   // t+1 landed
      asm volatile("s_barrier" ::: "memory");            // cur fully read
    }
  }

  // epilogue (round-0 verified): col = lane&15 slot, row = quad*4 + reg
#pragma unroll
  for (int ni = 0; ni < 4; ++ni) {
    const int col = blockN + wn * 64 + ni * 16 + lr;
    const float swv = sw[col];
    const float bv = bias[col];
#pragma unroll
    for (int mi = 0; mi < 4; ++mi) {
      const int row0 = blockM + wm * 64 + mi * 16 + q * 4;
#pragma unroll
      for (int r = 0; r < 4; ++r) {
        const float s = sx[row0 + r] * swv;
        out[(size_t)(row0 + r) * N_DIM + col] = (float)acc[mi][ni][r] * s + bv;
      }
    }
  }
}

extern "C" void kernel_launch(void* const* d_in, const int* in_sizes, int n_in,
                              void* d_out, int out_size, void* d_ws, size_t ws_size,
                              hipStream_t stream) {
  const float* x      = (const float*)d_in[0];
  const float* cs     = (const float*)d_in[1];
  const u32*   qw     = (const u32*)d_in[2];
  const int*   perm   = (const int*)d_in[3];
  const float* scales = (const float*)d_in[4];
  const float* zeros  = (const float*)d_in[5];
  const float* bias   = (const float*)d_in[6];
  float* out = (float*)d_out;

  u8* xq = (u8*)d_ws;                               // 32 MiB: M*K i8 (natural)
  u8* wq = xq + (size_t)M_DIM * K_DIM;              // 16 MiB: N*K i8 (perm-scattered)
  float* sx = (float*)(wq + (size_t)N_DIM * K_DIM); // 32 KiB
  float* sw = sx + M_DIM;                           // 16 KiB

  hipLaunchKernelGGL(prep_all, dim3(N_DIM + M_DIM), dim3(256), 0, stream,
                     x, cs, qw, perm, scales, zeros, xq, wq, sx, sw);
  hipLaunchKernelGGL(gemm_i8, dim3((M_DIM / BM) * (N_DIM / BN)), dim3(256), 0,
                     stream, xq, wq, sx, sw, bias, out);
}